// Round 2
// baseline (3713.081 us; speedup 1.0000x reference)
//
#include <hip/hip_runtime.h>

#define B_ 256
#define T_ 512
#define H_ 512
#define P_ 128
#define G4 2048   // 4*H

using short8  = __attribute__((ext_vector_type(8))) short;
using floatx4 = __attribute__((ext_vector_type(4))) float;

__device__ __forceinline__ unsigned short f2bf(float f){
  union { float f; unsigned u; } uu; uu.f = f;
  unsigned u = uu.u;
  u = (u + 0x7FFFu + ((u >> 16) & 1u)) >> 16;
  return (unsigned short)u;
}
__device__ __forceinline__ float bf2f(unsigned short s){
  union { unsigned u; float f; } uu; uu.u = ((unsigned)s) << 16;
  return uu.f;
}
__device__ __forceinline__ float sigm(float x){ return 1.0f / (1.0f + __expf(-x)); }
__device__ __forceinline__ float tanh_(float x){ return 2.0f / (1.0f + __expf(-2.0f*x)) - 1.0f; }

__device__ __forceinline__ float wredsum(float v){
  #pragma unroll
  for (int off = 32; off; off >>= 1) v += __shfl_xor(v, off, 64);
  return v;
}

// Pack enc_Whh (2048x512 fp32, row-major [gate_col][k]) into bf16 MFMA
// B-fragment order, split into hi + lo residual (bf16x2 representation).
// idx = ((((nb*4+q)*2+t2)*16+kk)*64+lane)*8 + e
// col = q*512 + nb*32 + t2*16 + (lane&15);  k = kk*32 + (lane>>4)*8 + e
__global__ __launch_bounds__(256) void pack_w(const float* __restrict__ Whh,
                                              unsigned short* __restrict__ Wp_hi,
                                              unsigned short* __restrict__ Wp_lo){
  int p8   = blockIdx.x * 256 + threadIdx.x;   // 0..131071
  int lane = p8 & 63;
  int kk   = (p8 >> 6) & 15;
  int t2   = (p8 >> 10) & 1;
  int q    = (p8 >> 11) & 3;
  int nb   = (p8 >> 13) & 15;
  int col  = q*512 + nb*32 + t2*16 + (lane & 15);
  int k0   = kk*32 + (lane >> 4)*8;
  const float* s = Whh + (size_t)col * H_ + k0;
  unsigned short vh[8], vl[8];
  #pragma unroll
  for (int e = 0; e < 8; e++){
    float w = s[e];
    unsigned short hi = f2bf(w);
    vh[e] = hi;
    vl[e] = f2bf(w - bf2f(hi));
  }
  *(uint4*)(Wp_hi + (size_t)p8 * 8) = *(const uint4*)vh;
  *(uint4*)(Wp_lo + (size_t)p8 * 8) = *(const uint4*)vl;
}

__global__ __launch_bounds__(256) void bsum_k(const float* __restrict__ a,
                                              const float* __restrict__ b,
                                              float* __restrict__ o){
  int i = blockIdx.x * 256 + threadIdx.x;
  if (i < G4) o[i] = a[i] + b[i];
}

// One encoder time step. grid = (16 col-blocks, 16 batch-groups), 256 thr.
// Block (nb, gb): batch rows gb*16..+15, gate cols q*512 + nb*32..+31 (q=wave).
// h is kept as a bf16 hi/lo pair; S = Ah*Wh + Ah*Wl + Al*Wh  (fp32 acc).
// mode 0: normal; mode 1: + write fp32 h to hfp; mode 2: write Gconst = S + bsum.
__global__ __launch_bounds__(256) void enc_step(
    const unsigned short* __restrict__ Wp,       // hi, lo at +1048576
    const unsigned short* __restrict__ hin_hi,
    const unsigned short* __restrict__ hin_lo,
    unsigned short* __restrict__ hout_hi,
    unsigned short* __restrict__ hout_lo,
    float* __restrict__ c,
    const float* __restrict__ x,
    const float* __restrict__ Wih,
    const float* __restrict__ bsum,
    float* __restrict__ hfp,
    float* __restrict__ Gout,
    int t, int mode)
{
  __shared__ unsigned short As[2][16][520];   // [hi/lo][row][k], +8 pad
  __shared__ float Sg[4][16][32];
  const int nb = blockIdx.x, gb = blockIdx.y;
  const int tid = threadIdx.x;
  const int lane = tid & 63, wv = tid >> 6;
  const int r0 = gb * 16;

  // stage h hi+lo tiles (2 x 16 x 512 bf16) into LDS, 16B vector loads
  #pragma unroll
  for (int i = 0; i < 8; i++){
    int chunk = tid + i * 256;            // 0..2047
    int m     = chunk >> 10;              // 0=hi, 1=lo
    int rc    = chunk & 1023;
    int row   = rc >> 6;
    int col8  = (rc & 63) * 8;
    const unsigned short* src = m ? hin_lo : hin_hi;
    *(uint4*)&As[m][row][col8] = *(const uint4*)(src + (size_t)(r0 + row) * H_ + col8);
  }
  __syncthreads();

  floatx4 acc0 = {0.f,0.f,0.f,0.f};
  floatx4 acc1 = {0.f,0.f,0.f,0.f};
  const int arow = lane & 15;
  const int aoff = (lane >> 4) * 8;
  const unsigned short* wbh = Wp + (size_t)(nb*4 + wv) * 16384;            // 2 tiles * 8192
  const unsigned short* wbl = wbh + 1048576;

  #pragma unroll
  for (int kk = 0; kk < 16; kk++){
    short8 ah  = *(const short8*)&As[0][arow][kk*32 + aoff];
    short8 al  = *(const short8*)&As[1][arow][kk*32 + aoff];
    short8 b0h = *(const short8*)(wbh + (size_t)kk*512 + lane*8);
    short8 b1h = *(const short8*)(wbh + 8192 + (size_t)kk*512 + lane*8);
    short8 b0l = *(const short8*)(wbl + (size_t)kk*512 + lane*8);
    short8 b1l = *(const short8*)(wbl + 8192 + (size_t)kk*512 + lane*8);
    acc0 = __builtin_amdgcn_mfma_f32_16x16x32_bf16(ah, b0h, acc0, 0, 0, 0);
    acc0 = __builtin_amdgcn_mfma_f32_16x16x32_bf16(ah, b0l, acc0, 0, 0, 0);
    acc0 = __builtin_amdgcn_mfma_f32_16x16x32_bf16(al, b0h, acc0, 0, 0, 0);
    acc1 = __builtin_amdgcn_mfma_f32_16x16x32_bf16(ah, b1h, acc1, 0, 0, 0);
    acc1 = __builtin_amdgcn_mfma_f32_16x16x32_bf16(ah, b1l, acc1, 0, 0, 0);
    acc1 = __builtin_amdgcn_mfma_f32_16x16x32_bf16(al, b1h, acc1, 0, 0, 0);
  }

  // C/D layout: col = lane&15, row = (lane>>4)*4 + reg   [m89-verified]
  #pragma unroll
  for (int r = 0; r < 4; r++){
    int row = (lane >> 4) * 4 + r;
    Sg[wv][row][lane & 15]        = acc0[r];
    Sg[wv][row][16 + (lane & 15)] = acc1[r];
  }
  __syncthreads();

  if (mode == 2){
    #pragma unroll
    for (int e = 0; e < 2; e++){
      int idx = tid + e * 256;
      int row = idx >> 5, col = idx & 31;
      int b = r0 + row, hc = nb*32 + col;
      #pragma unroll
      for (int q = 0; q < 4; q++)
        Gout[(size_t)b * G4 + q*512 + hc] = Sg[q][row][col] + bsum[q*512 + hc];
    }
    return;
  }

  #pragma unroll
  for (int e = 0; e < 2; e++){
    int idx = tid + e * 256;
    int row = idx >> 5, col = idx & 31;
    int b = r0 + row, hc = nb*32 + col;
    float xb = x[(size_t)b * T_ + t];
    float ip = Sg[0][row][col] + xb * Wih[hc]        + bsum[hc];
    float fp = Sg[1][row][col] + xb * Wih[512 + hc]  + bsum[512 + hc];
    float gp = Sg[2][row][col] + xb * Wih[1024 + hc] + bsum[1024 + hc];
    float op = Sg[3][row][col] + xb * Wih[1536 + hc] + bsum[1536 + hc];
    float i_ = sigm(ip), f_ = sigm(fp), g_ = tanh_(gp), o_ = sigm(op);
    size_t ci = (size_t)b * H_ + hc;
    float c2 = f_ * c[ci] + i_ * g_;
    float h2 = o_ * tanh_(c2);
    c[ci] = c2;
    unsigned short hh = f2bf(h2);
    hout_hi[ci] = hh;
    hout_lo[ci] = f2bf(h2 - bf2f(hh));
    if (mode == 1) hfp[ci] = h2;
  }
}

// Decoder: scalar recurrence per batch row, one wave per row, zero syncs.
// y <- db + sum_j dW[j] * LSTMh_j(y)  with fixed (Gconst, c).
__global__ __launch_bounds__(256) void decoder(
    const float* __restrict__ G, const float* __restrict__ c,
    const float* __restrict__ hfp, const float* __restrict__ Wih,
    const float* __restrict__ dW, const float* __restrict__ db,
    float* __restrict__ out)
{
  const int row  = blockIdx.x * 4 + (threadIdx.x >> 6);
  const int lane = threadIdx.x & 63;
  float Gr[4][8], wr[4][8], cc[8], wd[8];
  float p = 0.f;
  #pragma unroll
  for (int k = 0; k < 8; k++){
    int j = lane + k * 64;
    cc[k] = c[(size_t)row * H_ + j];
    wd[k] = dW[j];
    #pragma unroll
    for (int q = 0; q < 4; q++){
      Gr[q][k] = G[(size_t)row * G4 + q*512 + j];
      wr[q][k] = Wih[q*512 + j];
    }
    p += hfp[(size_t)row * H_ + j] * wd[k];
  }
  const float bias = db[0];
  float y = wredsum(p) + bias;
  for (int tt = 0; tt < P_; tt++){
    if (lane == 0) out[(size_t)row * P_ + tt] = y;
    if (tt == P_ - 1) break;
    float pp = 0.f;
    #pragma unroll
    for (int k = 0; k < 8; k++){
      float i_ = sigm (y * wr[0][k] + Gr[0][k]);
      float f_ = sigm (y * wr[1][k] + Gr[1][k]);
      float g_ = tanh_(y * wr[2][k] + Gr[2][k]);
      float o_ = sigm (y * wr[3][k] + Gr[3][k]);
      float c2 = f_ * cc[k] + i_ * g_;
      pp += o_ * tanh_(c2) * wd[k];
    }
    y = wredsum(pp) + bias;
  }
}

extern "C" void kernel_launch(void* const* d_in, const int* in_sizes, int n_in,
                              void* d_out, int out_size, void* d_ws, size_t ws_size,
                              hipStream_t stream)
{
  const float* x    = (const float*)d_in[0];
  const float* Wih  = (const float*)d_in[1];
  const float* Whh  = (const float*)d_in[2];
  const float* bih  = (const float*)d_in[3];
  const float* bhh  = (const float*)d_in[4];
  // d_in[5..8] = dec_* : provably unused by the reference output
  const float* dW   = (const float*)d_in[9];
  const float* db   = (const float*)d_in[10];
  float* out = (float*)d_out;

  unsigned short* Wp   = (unsigned short*)d_ws;  // hi: 1048576 u16, lo: 1048576 u16 (4 MB)
  unsigned short* h0h  = Wp + 2097152;           // 131072 u16
  unsigned short* h0l  = h0h + 131072;
  unsigned short* h1h  = h0l + 131072;
  unsigned short* h1l  = h1h + 131072;           // (1 MB total h buffers)
  float* c    = (float*)(h1l + 131072);          // 131072 f32
  float* hfp  = c + 131072;                      // 131072 f32
  float* G    = hfp + 131072;                    // 524288 f32   (2 MB)
  float* bsum = G + 524288;                      // 2048 f32

  hipMemsetAsync(h0h, 0, 2 * 131072 * sizeof(unsigned short), stream);  // h0 hi+lo
  hipMemsetAsync(c,   0, 131072 * sizeof(float), stream);
  pack_w<<<512, 256, 0, stream>>>(Whh, Wp, Wp + 1048576);
  bsum_k<<<8, 256, 0, stream>>>(bih, bhh, bsum);

  for (int t = 0; t < T_; t++){
    const unsigned short* hih = (t & 1) ? h1h : h0h;
    const unsigned short* hil = (t & 1) ? h1l : h0l;
    unsigned short* hoh = (t & 1) ? h0h : h1h;
    unsigned short* hol = (t & 1) ? h0l : h1l;
    enc_step<<<dim3(16,16), 256, 0, stream>>>(Wp, hih, hil, hoh, hol, c, x, Wih,
                                              bsum, hfp, nullptr, t,
                                              (t == T_-1) ? 1 : 0);
  }
  // Gconst = h_final @ Whh^T + bsum   (h_final is in h0 pair after t=511)
  enc_step<<<dim3(16,16), 256, 0, stream>>>(Wp, h0h, h0l, h1h, h1l, c, x, Wih,
                                            bsum, hfp, G, 0, 2);
  decoder<<<64, 256, 0, stream>>>(G, c, hfp, Wih, dW, db, out);
}